// Round 9
// baseline (799.928 us; speedup 1.0000x reference)
//
#include <hip/hip_runtime.h>

typedef __bf16 bf16x8 __attribute__((ext_vector_type(8)));
typedef float f32x4 __attribute__((ext_vector_type(4)));

// LDS-only barrier: does NOT drain vmcnt, so global prefetch loads / fire-and-forget
// stores stay in flight across the barrier (CK block_sync_lds pattern).
__device__ __forceinline__ void sync_lds() {
    asm volatile("s_waitcnt lgkmcnt(0)" ::: "memory");
    __builtin_amdgcn_s_barrier();
}

// ---------------- fused prep: [0,8160) DFT basis | [8160,38400) frames | [38400,39680) WT ----------------
__global__ __launch_bounds__(256) void prep_kernel(
    const float* __restrict__ x, const float* __restrict__ w_ih_f, const float* __restrict__ w_ih_b,
    __bf16* __restrict__ BT, __bf16* __restrict__ A, __bf16* __restrict__ WT)
{
    int blk = blockIdx.x;
    if (blk < 8160) {                       // ---- DFT basis (v_cos/v_sin take REVOLUTIONS)
        int id = blk * 256 + threadIdx.x;   // < 2176*960
        int n = id / 960;
        int j = id - n * 960;
        float v = 0.f;
        if (n < 2050) {
            int k = n >> 1;
            int p = (k * (544 + j)) & 2047;             // exact integer phase reduction
            float pr = (float)p * (1.0f / 2048.0f);     // revolutions
            v = (n & 1) ? __builtin_amdgcn_sinf(pr) : __builtin_amdgcn_cosf(pr);
        }
        BT[id] = (__bf16)v;
    } else if (blk < 38400) {               // ---- windowed frames: A[frame][j] = xp[t*240+544+j]*hann960[j]
        int id = (blk - 8160) * 256 + threadIdx.x;      // one thread per 2 cols, < 16128*480
        int frame = id / 480;
        int jp = (id - frame * 480) * 2;
        float v[2] = {0.f, 0.f};
        if (frame < 16016) {
            int b = frame / 1001;
            int t = frame - b * 1001;
            const float* xb = x + (size_t)b * 240000;
            #pragma unroll
            for (int e = 0; e < 2; ++e) {
                int j = jp + e;
                int s = t * 240 + j - 480;              // xp index minus pad
                if (s < 0) s = -s;                      // left reflect
                else if (s >= 240000) s = 479998 - s;   // right reflect (2L-2-s)
                float win = 0.5f - 0.5f * __builtin_amdgcn_cosf((float)j * (1.0f / 960.0f));
                v[e] = xb[s] * win;
            }
        }
        union { unsigned int u; __bf16 h[2]; } pk;
        pk.h[0] = (__bf16)v[0]; pk.h[1] = (__bf16)v[1];
        *reinterpret_cast<unsigned int*>(&A[(size_t)frame * 960 + jp]) = pk.u;
    } else {                                // ---- stacked input-proj weights, transposed + K-padded
        int id = (blk - 38400) * 256 + threadIdx.x;     // < 1024*320
        int n = id / 320;
        int k = id - n * 320;
        float v = 0.f;
        if (k < 301) v = (n < 512) ? w_ih_f[n * 301 + k] : w_ih_b[(n - 512) * 301 + k];
        WT[id] = (__bf16)v;
    }
}

// ---------------- DFT GEMM, Cdft = A(M x 960) * BT(2176 x 960)^T, bf16 out.
// m97-style staging: global_load_lds width=16 into unpadded 128x64 tiles; XOR swizzle
// chunk^=(row&7) applied on the GLOBAL side -> fragment ds_read_b128 conflict-light. ----------------
__global__ __launch_bounds__(256) void gemm_kernel(
    const __bf16* __restrict__ A, const __bf16* __restrict__ BT,
    int Ka, int kIters, __bf16* __restrict__ Cdft)
{
    __shared__ __bf16 As[128 * 64];
    __shared__ __bf16 Bs[128 * 64];
    const int tid = threadIdx.x;
    const int wave = tid >> 6, lane = tid & 63, l15 = lane & 15, quad = lane >> 4;
    const int bn = blockIdx.x, bm = blockIdx.y;
    const int qm = wave >> 1, qn = wave & 1;
    f32x4 acc[4][4] = {};
    const int rl  = lane >> 3;            // row within 8-row chunk
    const int gch = (lane & 7) ^ rl;      // swizzled global 16B-chunk within the 64-col row
    const __bf16* Ag = A + (size_t)(bm * 128) * Ka;
    const __bf16* Bg = BT + (size_t)(bn * 128) * Ka;

    for (int kb = 0; kb < kIters; ++kb) {
        int k0 = kb * 64;
        #pragma unroll
        for (int p = 0; p < 4; ++p) {
            int c = wave + p * 4;          // 16 chunk-instructions cover 128 rows (8 rows each)
            int row = c * 8 + rl;
            __builtin_amdgcn_global_load_lds(
                (const __attribute__((address_space(1))) void*)(Ag + (size_t)row * Ka + k0 + gch * 8),
                (__attribute__((address_space(3))) void*)(As + c * 512), 16, 0, 0);
            __builtin_amdgcn_global_load_lds(
                (const __attribute__((address_space(1))) void*)(Bg + (size_t)row * Ka + k0 + gch * 8),
                (__attribute__((address_space(3))) void*)(Bs + c * 512), 16, 0, 0);
        }
        __syncthreads();
        #pragma unroll
        for (int ks = 0; ks < 2; ++ks) {
            bf16x8 af[4], bfr[4];
            #pragma unroll
            for (int i = 0; i < 4; ++i) {
                int row = qm * 64 + i * 16 + l15;
                int ch = (ks * 4 + quad) ^ (l15 & 7);
                af[i] = *reinterpret_cast<const bf16x8*>(&As[row * 64 + ch * 8]);
            }
            #pragma unroll
            for (int j = 0; j < 4; ++j) {
                int row = qn * 64 + j * 16 + l15;
                int ch = (ks * 4 + quad) ^ (l15 & 7);
                bfr[j] = *reinterpret_cast<const bf16x8*>(&Bs[row * 64 + ch * 8]);
            }
            #pragma unroll
            for (int i = 0; i < 4; ++i)
                #pragma unroll
                for (int j = 0; j < 4; ++j)
                    acc[i][j] = __builtin_amdgcn_mfma_f32_16x16x32_bf16(af[i], bfr[j], acc[i][j], 0, 0, 0);
        }
        __syncthreads();
    }

    #pragma unroll
    for (int i = 0; i < 4; ++i)
        #pragma unroll
        for (int j = 0; j < 4; ++j) {
            int n = bn * 128 + qn * 64 + j * 16 + l15;
            #pragma unroll
            for (int r = 0; r < 4; ++r) {
                int m = bm * 128 + qm * 64 + i * 16 + quad * 4 + r;
                Cdft[(size_t)m * 2176 + n] = (__bf16)acc[i][j][r];
            }
        }
}

// ---------------- fused feature-build + input projection: 126 blocks (one per M-tile).
// feat tile (128 frames x 320) computed ON THE FLY into LDS (gather from Cdft + log);
// then 8 bn-tiles x 5 kb: B (WT) double-buffered via global_load_lds (R8 XOR swizzle),
// prefetch overlapped with the MFMA phase. Epilogue scatters fp32 into
// pre[t][dir][batch][cell][gate] with bias. ----------------
__global__ __launch_bounds__(256) void proj_kernel(
    const float* __restrict__ f0, const __bf16* __restrict__ Cdft,
    const __bf16* __restrict__ WT, const float* __restrict__ b_f, const float* __restrict__ b_b,
    float* __restrict__ pre)
{
    __shared__ __bf16 Afeat[128 * 328];   // stride 328 -> row offset 4 banks: 2-way on b128 = free
    __shared__ __bf16 Bs[2][128 * 64];
    const int tid = threadIdx.x;
    const int wave = tid >> 6, lane = tid & 63, l15 = lane & 15, quad = lane >> 4;
    const int bm = blockIdx.x;
    const int qm = wave >> 1, qn = wave & 1;
    const int rl  = lane >> 3;
    const int gch = (lane & 7) ^ rl;
    const float LN2 = 0.6931471805599453f;

    // ---- feat tile into LDS
    for (int idx = tid; idx < 128 * 320; idx += 256) {
        int fl = idx / 320;
        int d  = idx - fl * 320;
        int frame = bm * 128 + fl;
        float val = 0.f;
        if (frame < 16016) {
            int b = frame / 1001;
            int t = frame - b * 1001;
            float f0v = f0[b * 1001 + t];
            float f0nz = (f0v > 0.f) ? f0v : 80.f;   // SR/NUM_BANDS*0.5
            if (d < 300) {
                float mult = (d == 0) ? 0.5f : (float)(d + 1) * 0.5f;
                int kidx = (int)rintf(f0nz * mult * (1.0f / 11.71875f));
                kidx = min(max(kidx, 0), 1024);
                float e = 0.f;
                if (kidx < 1024) {   // bin 1024 forced to zero by reference
                    unsigned int pk = *reinterpret_cast<const unsigned int*>(&Cdft[(size_t)frame * 2176 + 2 * kidx]);
                    union { unsigned int u; __bf16 h[2]; } c; c.u = pk;
                    float c0 = (float)c.h[0], c1 = (float)c.h[1];
                    e = c0 * c0 + c1 * c1;
                }
                val = (__builtin_amdgcn_logf(e + 1e-8f) * LN2 + 18.f) * (1.f / 23.f);
            } else if (d == 300) {
                val = __builtin_amdgcn_logf(f0nz) * LN2;
            }
        }
        Afeat[fl * 328 + d] = (__bf16)val;
    }

    // issue B tile for iter 0 (bn=0, kb=0)
    #pragma unroll
    for (int p = 0; p < 4; ++p) {
        int c = wave + p * 4;
        int row = c * 8 + rl;
        __builtin_amdgcn_global_load_lds(
            (const __attribute__((address_space(1))) void*)(WT + (size_t)row * 320 + gch * 8),
            (__attribute__((address_space(3))) void*)(&Bs[0][c * 512]), 16, 0, 0);
    }
    __syncthreads();   // Afeat + Bs[0] ready

    f32x4 acc[4][4];
    for (int iter = 0; iter < 40; ++iter) {
        int bn = iter / 5, kb = iter - bn * 5;
        if (iter + 1 < 40) {   // prefetch next B tile; overlapped with this iter's MFMAs
            int it2 = iter + 1;
            int bn2 = it2 / 5, kb2 = it2 - bn2 * 5;
            const __bf16* Bg = WT + (size_t)(bn2 * 128) * 320 + kb2 * 64;
            #pragma unroll
            for (int p = 0; p < 4; ++p) {
                int c = wave + p * 4;
                int row = c * 8 + rl;
                __builtin_amdgcn_global_load_lds(
                    (const __attribute__((address_space(1))) void*)(Bg + (size_t)row * 320 + gch * 8),
                    (__attribute__((address_space(3))) void*)(&Bs[it2 & 1][c * 512]), 16, 0, 0);
            }
        }
        if (kb == 0) {
            #pragma unroll
            for (int i = 0; i < 4; ++i)
                #pragma unroll
                for (int j = 0; j < 4; ++j)
                    acc[i][j] = (f32x4){0.f, 0.f, 0.f, 0.f};
        }
        const __bf16* Bsr = Bs[iter & 1];
        #pragma unroll
        for (int ks = 0; ks < 2; ++ks) {
            bf16x8 af[4], bfr[4];
            #pragma unroll
            for (int i = 0; i < 4; ++i)
                af[i] = *reinterpret_cast<const bf16x8*>(&Afeat[(qm * 64 + i * 16 + l15) * 328 + kb * 64 + ks * 32 + quad * 8]);
            #pragma unroll
            for (int j = 0; j < 4; ++j) {
                int row = qn * 64 + j * 16 + l15;
                int ch = (ks * 4 + quad) ^ (l15 & 7);
                bfr[j] = *reinterpret_cast<const bf16x8*>(&Bsr[row * 64 + ch * 8]);
            }
            #pragma unroll
            for (int i = 0; i < 4; ++i)
                #pragma unroll
                for (int j = 0; j < 4; ++j)
                    acc[i][j] = __builtin_amdgcn_mfma_f32_16x16x32_bf16(af[i], bfr[j], acc[i][j], 0, 0, 0);
        }
        if (kb == 4) {   // epilogue for this bn
            for (int i = 0; i < 4; ++i)
                for (int j = 0; j < 4; ++j) {
                    int n = bn * 128 + qn * 64 + j * 16 + l15;   // n < 1024
                    float bias = (n < 512) ? b_f[n] : b_b[n - 512];
                    int dirg = n >> 9;
                    int ngate = n & 511;
                    int g = ngate >> 7;          // gate: 0=i 1=f 2=g 3=o
                    int jj = ngate & 127;        // hidden unit
                    for (int r = 0; r < 4; ++r) {
                        int m = bm * 128 + qm * 64 + i * 16 + quad * 4 + r;
                        if (m < 16016) {
                            int b = m / 1001;
                            int t = m - b * 1001;
                            size_t off = ((size_t)(t * 2 + dirg) * 16 + b) * 512 + jj * 4 + g;
                            pre[off] = acc[i][j][r] + bias;
                        }
                    }
                }
        }
        __syncthreads();   // drains prefetch loads (and epilogue stores); next buffer safe
    }
}

// ---------------- batch-parallel BiLSTM: 32 blocks = (batch 16) x (dir 2), one CU each.
// (unchanged from R7 — at ~1090 cyc/step it is near its bf16 structural floor:
//  ds_read ~120 + MFMA pipe ~620 (128 insts/CU) + gate chain ~150 + barrier tails) ----------------
__global__ __launch_bounds__(512, 2) void lstm_kernel(
    const float* __restrict__ w_hh_f, const float* __restrict__ w_hh_b,
    const float* __restrict__ pre, float* __restrict__ h_out)
{
    const int bid = blockIdx.x;          // 0..31
    const int b   = bid & 15;
    const int dir = bid >> 4;
    const float* w_hh = dir ? w_hh_b : w_hh_f;
    const int tid = threadIdx.x;
    const int wave = tid >> 6, lane = tid & 63, l15 = lane & 15, quad = lane >> 4;
    const int msel = l15 >> 2;
    const bool own = (quad == (l15 & 3));    // this lane owns cell cellj
    const int cellj = wave * 16 + l15;

    __shared__ __bf16 h_lds[2][128];     // double-buffered h(t)

    // A-fragments: perm row s = wave*64 + mt*16 + l15; W_hh row = (s&3)*128 + (s>>2)
    bf16x8 afrag[4][4];
    #pragma unroll
    for (int mt = 0; mt < 4; ++mt) {
        int s = wave * 64 + mt * 16 + l15;
        const float* wrow = w_hh + (size_t)((s & 3) * 128 + (s >> 2)) * 128;
        #pragma unroll
        for (int kt = 0; kt < 4; ++kt) {
            bf16x8 v;
            #pragma unroll
            for (int e = 0; e < 8; ++e) v[e] = (__bf16)wrow[kt * 32 + quad * 8 + e];
            afrag[mt][kt] = v;
        }
    }

    if (tid < 128) h_lds[0][tid] = (__bf16)0.f;

    const int t0 = dir ? 1000 : 0;
    const ptrdiff_t pre_sstride  = dir ? -16384 : 16384;   // floats per step
    const ptrdiff_t hout_sstride = dir ? -2048  : 2048;    // floats per step
    const float* pre_base = pre + ((size_t)(t0 * 2 + dir) * 16 + b) * 512 + (size_t)cellj * 4;
    float* hout_base = h_out + (((size_t)dir * 1001 + t0) * 16 + b) * 128;

    float cstate = 0.f;
    const float L2E = 1.4426950408889634f;

    auto body = [&](int s, f32x4 P) {
        const __bf16* hb = h_lds[s & 1];
        bf16x8 bfr[4];
        #pragma unroll
        for (int kt = 0; kt < 4; ++kt)
            bfr[kt] = *reinterpret_cast<const bf16x8*>(&hb[kt * 32 + quad * 8]);

        f32x4 acc[4] = {};
        #pragma unroll
        for (int kt = 0; kt < 4; ++kt)
            #pragma unroll
            for (int mt = 0; mt < 4; ++mt)
                acc[mt] = __builtin_amdgcn_mfma_f32_16x16x32_bf16(afrag[mt][kt], bfr[kt], acc[mt], 0, 0, 0);

        // z4 = acc[msel] (valid on lanes with quad == (l15&3))
        f32x4 t01 = (msel & 1) ? acc[1] : acc[0];
        f32x4 t23 = (msel & 1) ? acc[3] : acc[2];
        f32x4 z4  = (msel & 2) ? t23 : t01;

        float zi = z4[0] + P[0], zf = z4[1] + P[1];
        float zg = z4[2] + P[2], zo = z4[3] + P[3];
        // fused gates: 5 exp2 + 3 rcp, exact algebra
        float A = __builtin_amdgcn_exp2f(-L2E * zi);
        float B = __builtin_amdgcn_exp2f(-L2E * zf);
        float C = __builtin_amdgcn_exp2f(-2.f * L2E * zg);
        float D = __builtin_amdgcn_exp2f(-L2E * zo);
        float Pp = (1.f + A) * (1.f + C);
        float Q = 1.f + B;
        float cn = (cstate * Pp + (1.f - C) * Q) * __builtin_amdgcn_rcpf(Pp * Q);
        if (own) cstate = cn;
        float E = __builtin_amdgcn_exp2f(-2.f * L2E * cn);
        float h = (1.f - E) * __builtin_amdgcn_rcpf((1.f + D) * (1.f + E));

        if (own) {
            h_lds[(s + 1) & 1][cellj] = (__bf16)h;
            hout_base[(ptrdiff_t)s * hout_sstride + cellj] = h;   // fire-and-forget
        }
    };

    auto load_pre = [&](int sidx) -> f32x4 {
        return *reinterpret_cast<const f32x4*>(pre_base + (ptrdiff_t)sidx * pre_sstride);
    };

    f32x4 PA = load_pre(0);
    f32x4 PB = load_pre(1);
    __syncthreads();   // h_lds[0] init visible

    for (int s = 0; s < 1001; s += 2) {
        body(s, PA);
        PA = load_pre(s + 2);   // unconditional: pre is padded +-2 steps
        sync_lds();
        if (s + 1 < 1001) {
            body(s + 1, PB);
            PB = load_pre(s + 3);
            sync_lds();
        }
    }
}

// ---------------- LayerNorm + out projection via MFMA: 1001 blocks x 16 rows.
// LN per wave (4 rows), hn staged bf16 in LDS, then 16x64x256 GEMM = 8 MFMAs/wave
// (wave w covers out-cols w*16..w*16+15). ----------------
__global__ __launch_bounds__(256) void out_kernel(
    const float* __restrict__ h_out, const float* __restrict__ ln_g, const float* __restrict__ ln_b,
    const float* __restrict__ out_w, const float* __restrict__ out_b, float* __restrict__ out)
{
    __shared__ __bf16 hn_lds[16 * 264];   // stride 264 -> 2-way on b128 = free
    const int tid = threadIdx.x;
    const int wave = tid >> 6, lane = tid & 63, l15 = lane & 15, quad = lane >> 4;

    float lg0 = ln_g[lane],        lb0 = ln_b[lane];
    float lg1 = ln_g[64 + lane],   lb1 = ln_b[64 + lane];
    float lg2 = ln_g[128 + lane],  lb2 = ln_b[128 + lane];
    float lg3 = ln_g[192 + lane],  lb3 = ln_b[192 + lane];

    #pragma unroll
    for (int rr = 0; rr < 4; ++rr) {
        int wrow = wave * 4 + rr;
        int r = blockIdx.x * 16 + wrow;            // 1001*16 = 16016 exactly: no guard
        int b = r / 1001, t = r - b * 1001;
        size_t basef = ((size_t)t * 16 + b) * 128;            // dir 0
        size_t baseb = ((size_t)(1001 + t) * 16 + b) * 128;   // dir 1
        float h0 = h_out[basef + lane];
        float h1 = h_out[basef + 64 + lane];
        float h2 = h_out[baseb + lane];
        float h3 = h_out[baseb + 64 + lane];
        float s1 = h0 + h1 + h2 + h3;
        float s2 = h0 * h0 + h1 * h1 + h2 * h2 + h3 * h3;
        #pragma unroll
        for (int m = 32; m >= 1; m >>= 1) {
            s1 += __shfl_xor(s1, m, 64);
            s2 += __shfl_xor(s2, m, 64);
        }
        float mu = s1 * (1.f / 256.f);
        float var = s2 * (1.f / 256.f) - mu * mu;   // biased var, matches jnp var
        float rstd = rsqrtf(var + 1e-5f);
        hn_lds[wrow * 264 + lane]       = (__bf16)((h0 - mu) * rstd * lg0 + lb0);
        hn_lds[wrow * 264 + 64 + lane]  = (__bf16)((h1 - mu) * rstd * lg1 + lb1);
        hn_lds[wrow * 264 + 128 + lane] = (__bf16)((h2 - mu) * rstd * lg2 + lb2);
        hn_lds[wrow * 264 + 192 + lane] = (__bf16)((h3 - mu) * rstd * lg3 + lb3);
    }
    __syncthreads();

    // GEMM: out[16 rows][64 cols] = hn(16x256) . out_w(64x256)^T; wave covers 16 cols
    const int o = wave * 16 + l15;
    f32x4 accA = {}, accB = {};
    #pragma unroll
    for (int kt = 0; kt < 8; ++kt) {
        bf16x8 a = *reinterpret_cast<const bf16x8*>(&hn_lds[l15 * 264 + kt * 32 + quad * 8]);
        const float* wp = out_w + (size_t)o * 256 + kt * 32 + quad * 8;
        bf16x8 bv;
        #pragma unroll
        for (int e = 0; e < 8; ++e) bv[e] = (__bf16)wp[e];
        if (kt & 1) accB = __builtin_amdgcn_mfma_f32_16x16x32_bf16(a, bv, accB, 0, 0, 0);
        else        accA = __builtin_amdgcn_mfma_f32_16x16x32_bf16(a, bv, accA, 0, 0, 0);
    }
    f32x4 acc = accA + accB;
    float ob = out_b[o];
    #pragma unroll
    for (int rc = 0; rc < 4; ++rc) {
        int r = blockIdx.x * 16 + quad * 4 + rc;
        out[(size_t)r * 64 + o] = acc[rc] + ob;
    }
}

extern "C" void kernel_launch(void* const* d_in, const int* in_sizes, int n_in,
                              void* d_out, int out_size, void* d_ws, size_t ws_size,
                              hipStream_t stream) {
    const float* x      = (const float*)d_in[0];
    const float* f0     = (const float*)d_in[1];
    const float* w_ih_f = (const float*)d_in[2];
    const float* w_hh_f = (const float*)d_in[3];
    const float* b_f    = (const float*)d_in[4];
    const float* w_ih_b = (const float*)d_in[5];
    const float* w_hh_b = (const float*)d_in[6];
    const float* b_b    = (const float*)d_in[7];
    const float* ln_g   = (const float*)d_in[8];
    const float* ln_b   = (const float*)d_in[9];
    const float* out_w  = (const float*)d_in[10];
    const float* out_b  = (const float*)d_in[11];
    float* out = (float*)d_out;

    char* ws = (char*)d_ws;
    size_t off = 0;
    auto alloc = [&](size_t bytes) { size_t o = off; off = (off + bytes + 255) & ~(size_t)255; return o; };
    __bf16* A     = (__bf16*)(ws + alloc((size_t)16128 * 960 * 2));
    __bf16* BT    = (__bf16*)(ws + alloc((size_t)2176 * 960 * 2));
    __bf16* Cdft  = (__bf16*)(ws + alloc((size_t)16128 * 2176 * 2));
    __bf16* WT    = (__bf16*)(ws + alloc((size_t)1024 * 320 * 2));
    // pre padded +-2 timesteps so the LSTM prefetch needs no bounds check
    float*  preA  = (float*)(ws + alloc((size_t)(1001 * 2 + 8) * 16 * 512 * 4));
    float*  pre   = preA + (size_t)4 * 16 * 512;
    float*  h_out = (float*)(ws + alloc((size_t)2 * 1001 * 16 * 128 * 4));
    (void)ws_size; (void)in_sizes; (void)n_in; (void)out_size;

    prep_kernel <<<39680, 256, 0, stream>>>(x, w_ih_f, w_ih_b, BT, A, WT);
    gemm_kernel <<<dim3(17, 126), 256, 0, stream>>>(A, BT, 960, 15, Cdft);
    proj_kernel <<<126, 256, 0, stream>>>(f0, Cdft, WT, b_f, b_b, pre);
    lstm_kernel <<<32, 512, 0, stream>>>(w_hh_f, w_hh_b, pre, h_out);
    out_kernel  <<<1001, 256, 0, stream>>>(h_out, ln_g, ln_b, out_w, out_b, out);
}

// Round 10
// 718.660 us; speedup vs baseline: 1.1131x; 1.1131x over previous
//
#include <hip/hip_runtime.h>

typedef __bf16 bf16x8 __attribute__((ext_vector_type(8)));
typedef float f32x4 __attribute__((ext_vector_type(4)));

// LDS-only barrier: does NOT drain vmcnt, so global prefetch loads / fire-and-forget
// stores stay in flight across the barrier (CK block_sync_lds pattern).
__device__ __forceinline__ void sync_lds() {
    asm volatile("s_waitcnt lgkmcnt(0)" ::: "memory");
    __builtin_amdgcn_s_barrier();
}

// ---------------- fused prep: [0,8160) DFT basis | [8160,38400) frames | [38400,39680) WT ----------------
__global__ __launch_bounds__(256) void prep_kernel(
    const float* __restrict__ x, const float* __restrict__ w_ih_f, const float* __restrict__ w_ih_b,
    __bf16* __restrict__ BT, __bf16* __restrict__ A, __bf16* __restrict__ WT)
{
    int blk = blockIdx.x;
    if (blk < 8160) {                       // ---- DFT basis (v_cos/v_sin take REVOLUTIONS)
        int id = blk * 256 + threadIdx.x;   // < 2176*960
        int n = id / 960;
        int j = id - n * 960;
        float v = 0.f;
        if (n < 2050) {
            int k = n >> 1;
            int p = (k * (544 + j)) & 2047;             // exact integer phase reduction
            float pr = (float)p * (1.0f / 2048.0f);     // revolutions
            v = (n & 1) ? __builtin_amdgcn_sinf(pr) : __builtin_amdgcn_cosf(pr);
        }
        BT[id] = (__bf16)v;
    } else if (blk < 38400) {               // ---- windowed frames: A[frame][j] = xp[t*240+544+j]*hann960[j]
        int id = (blk - 8160) * 256 + threadIdx.x;      // one thread per 2 cols, < 16128*480
        int frame = id / 480;
        int jp = (id - frame * 480) * 2;
        float v[2] = {0.f, 0.f};
        if (frame < 16016) {
            int b = frame / 1001;
            int t = frame - b * 1001;
            const float* xb = x + (size_t)b * 240000;
            #pragma unroll
            for (int e = 0; e < 2; ++e) {
                int j = jp + e;
                int s = t * 240 + j - 480;              // xp index minus pad
                if (s < 0) s = -s;                      // left reflect
                else if (s >= 240000) s = 479998 - s;   // right reflect (2L-2-s)
                float win = 0.5f - 0.5f * __builtin_amdgcn_cosf((float)j * (1.0f / 960.0f));
                v[e] = xb[s] * win;
            }
        }
        union { unsigned int u; __bf16 h[2]; } pk;
        pk.h[0] = (__bf16)v[0]; pk.h[1] = (__bf16)v[1];
        *reinterpret_cast<unsigned int*>(&A[(size_t)frame * 960 + jp]) = pk.u;
    } else {                                // ---- stacked input-proj weights, transposed + K-padded
        int id = (blk - 38400) * 256 + threadIdx.x;     // < 1024*320
        int n = id / 320;
        int k = id - n * 320;
        float v = 0.f;
        if (k < 301) v = (n < 512) ? w_ih_f[n * 301 + k] : w_ih_b[(n - 512) * 301 + k];
        WT[id] = (__bf16)v;
    }
}

// ---------------- bf16 MFMA GEMM, C = A(M x Ka) * BT(N x Ka)^T.  m97-style staging:
// global_load_lds width=16 into unpadded 128x64 tiles; XOR swizzle chunk^=(row&7) applied
// on the GLOBAL side -> fragment ds_read_b128 conflict-light. mode 0: DFT (store bf16 C);
// mode 1: input projection (scatter fp32 into [t][dir][batch][cell][gate] `pre` + bias). ----------------
__global__ __launch_bounds__(256) void gemm_kernel(
    const __bf16* __restrict__ A, const __bf16* __restrict__ BT,
    int Ka, int kIters, int mode,
    __bf16* __restrict__ Cdft, float* __restrict__ pre,
    const float* __restrict__ b_f, const float* __restrict__ b_b)
{
    __shared__ __bf16 As[128 * 64];
    __shared__ __bf16 Bs[128 * 64];
    const int tid = threadIdx.x;
    const int wave = tid >> 6, lane = tid & 63, l15 = lane & 15, quad = lane >> 4;
    const int bn = blockIdx.x, bm = blockIdx.y;
    const int qm = wave >> 1, qn = wave & 1;
    f32x4 acc[4][4] = {};
    const int rl  = lane >> 3;            // row within 8-row chunk
    const int gch = (lane & 7) ^ rl;      // swizzled global 16B-chunk within the 64-col row
    const __bf16* Ag = A + (size_t)(bm * 128) * Ka;
    const __bf16* Bg = BT + (size_t)(bn * 128) * Ka;

    for (int kb = 0; kb < kIters; ++kb) {
        int k0 = kb * 64;
        #pragma unroll
        for (int p = 0; p < 4; ++p) {
            int c = wave + p * 4;          // 16 chunk-instructions cover 128 rows (8 rows each)
            int row = c * 8 + rl;
            __builtin_amdgcn_global_load_lds(
                (const __attribute__((address_space(1))) void*)(Ag + (size_t)row * Ka + k0 + gch * 8),
                (__attribute__((address_space(3))) void*)(As + c * 512), 16, 0, 0);
            __builtin_amdgcn_global_load_lds(
                (const __attribute__((address_space(1))) void*)(Bg + (size_t)row * Ka + k0 + gch * 8),
                (__attribute__((address_space(3))) void*)(Bs + c * 512), 16, 0, 0);
        }
        __syncthreads();
        #pragma unroll
        for (int ks = 0; ks < 2; ++ks) {
            bf16x8 af[4], bfr[4];
            #pragma unroll
            for (int i = 0; i < 4; ++i) {
                int row = qm * 64 + i * 16 + l15;
                int ch = (ks * 4 + quad) ^ (l15 & 7);
                af[i] = *reinterpret_cast<const bf16x8*>(&As[row * 64 + ch * 8]);
            }
            #pragma unroll
            for (int j = 0; j < 4; ++j) {
                int row = qn * 64 + j * 16 + l15;
                int ch = (ks * 4 + quad) ^ (l15 & 7);
                bfr[j] = *reinterpret_cast<const bf16x8*>(&Bs[row * 64 + ch * 8]);
            }
            #pragma unroll
            for (int i = 0; i < 4; ++i)
                #pragma unroll
                for (int j = 0; j < 4; ++j)
                    acc[i][j] = __builtin_amdgcn_mfma_f32_16x16x32_bf16(af[i], bfr[j], acc[i][j], 0, 0, 0);
        }
        __syncthreads();
    }

    if (mode == 0) {
        #pragma unroll
        for (int i = 0; i < 4; ++i)
            #pragma unroll
            for (int j = 0; j < 4; ++j) {
                int n = bn * 128 + qn * 64 + j * 16 + l15;
                #pragma unroll
                for (int r = 0; r < 4; ++r) {
                    int m = bm * 128 + qm * 64 + i * 16 + quad * 4 + r;
                    Cdft[(size_t)m * 2176 + n] = (__bf16)acc[i][j][r];
                }
            }
    } else {
        for (int i = 0; i < 4; ++i)
            for (int j = 0; j < 4; ++j) {
                int n = bn * 128 + qn * 64 + j * 16 + l15;   // n < 1024
                float bias = (n < 512) ? b_f[n] : b_b[n - 512];
                int dirg = n >> 9;
                int ngate = n & 511;
                int g = ngate >> 7;          // gate index: 0=i 1=f 2=g 3=o
                int jj = ngate & 127;        // hidden unit
                for (int r = 0; r < 4; ++r) {
                    int m = bm * 128 + qm * 64 + i * 16 + quad * 4 + r;
                    if (m < 16016) {
                        int b = m / 1001;
                        int t = m - b * 1001;
                        // pre[t][dirg][batch b][cell jj][gate g]
                        size_t off = ((size_t)(t * 2 + dirg) * 16 + b) * 512 + jj * 4 + g;
                        pre[off] = acc[i][j][r] + bias;
                    }
                }
            }
    }
}

// ---------------- feature build: gather harmonic energies from bf16 DFT output ----------------
__global__ __launch_bounds__(320) void build_feat(const float* __restrict__ f0,
    const __bf16* __restrict__ Cdft, __bf16* __restrict__ feat)
{
    int frame = blockIdx.x;
    int d = threadIdx.x;   // 0..319
    float val = 0.f;
    const float LN2 = 0.6931471805599453f;
    {
        int b = frame / 1001;
        int t = frame - b * 1001;
        float f0v = f0[b * 1001 + t];
        float f0nz = (f0v > 0.f) ? f0v : 80.f;   // SR/NUM_BANDS*0.5
        if (d < 300) {
            float mult = (d == 0) ? 0.5f : (float)(d + 1) * 0.5f;
            int kidx = (int)rintf(f0nz * mult * (1.0f / 11.71875f));  // FREQ_INTERVAL = 24000/2048
            kidx = min(max(kidx, 0), 1024);
            float e = 0.f;
            if (kidx < 1024) {   // bin 1024 forced to zero by reference
                unsigned int pk = *reinterpret_cast<const unsigned int*>(&Cdft[(size_t)frame * 2176 + 2 * kidx]);
                union { unsigned int u; __bf16 h[2]; } c; c.u = pk;
                float c0 = (float)c.h[0], c1 = (float)c.h[1];
                e = c0 * c0 + c1 * c1;
            }
            val = (__builtin_amdgcn_logf(e + 1e-8f) * LN2 + 18.f) * (1.f / 23.f);
        } else if (d == 300) {
            val = __builtin_amdgcn_logf(f0nz) * LN2;
        }
    }
    feat[(size_t)frame * 320 + d] = (__bf16)val;
}

// ---------------- batch-parallel BiLSTM: 32 blocks = (batch 16) x (dir 2), one CU each.
// (unchanged from R7 — ~1090 cyc/step, near its bf16 structural floor:
//  ds_read ~120 + MFMA pipe ~620 (128 insts/CU) + gate chain ~150 + barrier tails) ----------------
__global__ __launch_bounds__(512, 2) void lstm_kernel(
    const float* __restrict__ w_hh_f, const float* __restrict__ w_hh_b,
    const float* __restrict__ pre, float* __restrict__ h_out)
{
    const int bid = blockIdx.x;          // 0..31
    const int b   = bid & 15;
    const int dir = bid >> 4;
    const float* w_hh = dir ? w_hh_b : w_hh_f;
    const int tid = threadIdx.x;
    const int wave = tid >> 6, lane = tid & 63, l15 = lane & 15, quad = lane >> 4;
    const int msel = l15 >> 2;
    const bool own = (quad == (l15 & 3));    // this lane owns cell cellj
    const int cellj = wave * 16 + l15;

    __shared__ __bf16 h_lds[2][128];     // double-buffered h(t)

    // A-fragments: perm row s = wave*64 + mt*16 + l15; W_hh row = (s&3)*128 + (s>>2)
    bf16x8 afrag[4][4];
    #pragma unroll
    for (int mt = 0; mt < 4; ++mt) {
        int s = wave * 64 + mt * 16 + l15;
        const float* wrow = w_hh + (size_t)((s & 3) * 128 + (s >> 2)) * 128;
        #pragma unroll
        for (int kt = 0; kt < 4; ++kt) {
            bf16x8 v;
            #pragma unroll
            for (int e = 0; e < 8; ++e) v[e] = (__bf16)wrow[kt * 32 + quad * 8 + e];
            afrag[mt][kt] = v;
        }
    }

    if (tid < 128) h_lds[0][tid] = (__bf16)0.f;

    const int t0 = dir ? 1000 : 0;
    const ptrdiff_t pre_sstride  = dir ? -16384 : 16384;   // floats per step
    const ptrdiff_t hout_sstride = dir ? -2048  : 2048;    // floats per step
    const float* pre_base = pre + ((size_t)(t0 * 2 + dir) * 16 + b) * 512 + (size_t)cellj * 4;
    float* hout_base = h_out + (((size_t)dir * 1001 + t0) * 16 + b) * 128;

    float cstate = 0.f;
    const float L2E = 1.4426950408889634f;

    auto body = [&](int s, f32x4 P) {
        const __bf16* hb = h_lds[s & 1];
        bf16x8 bfr[4];
        #pragma unroll
        for (int kt = 0; kt < 4; ++kt)
            bfr[kt] = *reinterpret_cast<const bf16x8*>(&hb[kt * 32 + quad * 8]);

        f32x4 acc[4] = {};
        #pragma unroll
        for (int kt = 0; kt < 4; ++kt)
            #pragma unroll
            for (int mt = 0; mt < 4; ++mt)
                acc[mt] = __builtin_amdgcn_mfma_f32_16x16x32_bf16(afrag[mt][kt], bfr[kt], acc[mt], 0, 0, 0);

        // z4 = acc[msel] (valid on lanes with quad == (l15&3))
        f32x4 t01 = (msel & 1) ? acc[1] : acc[0];
        f32x4 t23 = (msel & 1) ? acc[3] : acc[2];
        f32x4 z4  = (msel & 2) ? t23 : t01;

        float zi = z4[0] + P[0], zf = z4[1] + P[1];
        float zg = z4[2] + P[2], zo = z4[3] + P[3];
        // fused gates: 5 exp2 + 3 rcp, exact algebra
        float A = __builtin_amdgcn_exp2f(-L2E * zi);
        float B = __builtin_amdgcn_exp2f(-L2E * zf);
        float C = __builtin_amdgcn_exp2f(-2.f * L2E * zg);
        float D = __builtin_amdgcn_exp2f(-L2E * zo);
        float Pp = (1.f + A) * (1.f + C);
        float Q = 1.f + B;
        float cn = (cstate * Pp + (1.f - C) * Q) * __builtin_amdgcn_rcpf(Pp * Q);
        if (own) cstate = cn;
        float E = __builtin_amdgcn_exp2f(-2.f * L2E * cn);
        float h = (1.f - E) * __builtin_amdgcn_rcpf((1.f + D) * (1.f + E));

        if (own) {
            h_lds[(s + 1) & 1][cellj] = (__bf16)h;
            hout_base[(ptrdiff_t)s * hout_sstride + cellj] = h;   // fire-and-forget
        }
    };

    auto load_pre = [&](int sidx) -> f32x4 {
        return *reinterpret_cast<const f32x4*>(pre_base + (ptrdiff_t)sidx * pre_sstride);
    };

    f32x4 PA = load_pre(0);
    f32x4 PB = load_pre(1);
    __syncthreads();   // h_lds[0] init visible

    for (int s = 0; s < 1001; s += 2) {
        body(s, PA);
        PA = load_pre(s + 2);   // unconditional: pre is padded +-2 steps
        sync_lds();
        if (s + 1 < 1001) {
            body(s + 1, PB);
            PB = load_pre(s + 3);
            sync_lds();
        }
    }
}

// ---------------- LayerNorm + out projection via MFMA: 1001 blocks x 16 rows.
// LN per wave (4 rows), hn staged bf16 in LDS, then 16x64x256 GEMM = 8 MFMAs/wave
// (wave w covers out-cols w*16..w*16+15). ----------------
__global__ __launch_bounds__(256) void out_kernel(
    const float* __restrict__ h_out, const float* __restrict__ ln_g, const float* __restrict__ ln_b,
    const float* __restrict__ out_w, const float* __restrict__ out_b, float* __restrict__ out)
{
    __shared__ __bf16 hn_lds[16 * 264];   // stride 264 -> 2-way on b128 = free
    const int tid = threadIdx.x;
    const int wave = tid >> 6, lane = tid & 63, l15 = lane & 15, quad = lane >> 4;

    float lg0 = ln_g[lane],        lb0 = ln_b[lane];
    float lg1 = ln_g[64 + lane],   lb1 = ln_b[64 + lane];
    float lg2 = ln_g[128 + lane],  lb2 = ln_b[128 + lane];
    float lg3 = ln_g[192 + lane],  lb3 = ln_b[192 + lane];

    #pragma unroll
    for (int rr = 0; rr < 4; ++rr) {
        int wrow = wave * 4 + rr;
        int r = blockIdx.x * 16 + wrow;            // 1001*16 = 16016 exactly: no guard
        int b = r / 1001, t = r - b * 1001;
        size_t basef = ((size_t)t * 16 + b) * 128;            // dir 0
        size_t baseb = ((size_t)(1001 + t) * 16 + b) * 128;   // dir 1
        float h0 = h_out[basef + lane];
        float h1 = h_out[basef + 64 + lane];
        float h2 = h_out[baseb + lane];
        float h3 = h_out[baseb + 64 + lane];
        float s1 = h0 + h1 + h2 + h3;
        float s2 = h0 * h0 + h1 * h1 + h2 * h2 + h3 * h3;
        #pragma unroll
        for (int m = 32; m >= 1; m >>= 1) {
            s1 += __shfl_xor(s1, m, 64);
            s2 += __shfl_xor(s2, m, 64);
        }
        float mu = s1 * (1.f / 256.f);
        float var = s2 * (1.f / 256.f) - mu * mu;   // biased var, matches jnp var
        float rstd = rsqrtf(var + 1e-5f);
        hn_lds[wrow * 264 + lane]       = (__bf16)((h0 - mu) * rstd * lg0 + lb0);
        hn_lds[wrow * 264 + 64 + lane]  = (__bf16)((h1 - mu) * rstd * lg1 + lb1);
        hn_lds[wrow * 264 + 128 + lane] = (__bf16)((h2 - mu) * rstd * lg2 + lb2);
        hn_lds[wrow * 264 + 192 + lane] = (__bf16)((h3 - mu) * rstd * lg3 + lb3);
    }
    __syncthreads();

    // GEMM: out[16 rows][64 cols] = hn(16x256) . out_w(64x256)^T; wave covers 16 cols
    const int o = wave * 16 + l15;
    f32x4 accA = {}, accB = {};
    #pragma unroll
    for (int kt = 0; kt < 8; ++kt) {
        bf16x8 a = *reinterpret_cast<const bf16x8*>(&hn_lds[l15 * 264 + kt * 32 + quad * 8]);
        const float* wp = out_w + (size_t)o * 256 + kt * 32 + quad * 8;
        bf16x8 bv;
        #pragma unroll
        for (int e = 0; e < 8; ++e) bv[e] = (__bf16)wp[e];
        if (kt & 1) accB = __builtin_amdgcn_mfma_f32_16x16x32_bf16(a, bv, accB, 0, 0, 0);
        else        accA = __builtin_amdgcn_mfma_f32_16x16x32_bf16(a, bv, accA, 0, 0, 0);
    }
    f32x4 acc = accA + accB;
    float ob = out_b[o];
    #pragma unroll
    for (int rc = 0; rc < 4; ++rc) {
        int r = blockIdx.x * 16 + quad * 4 + rc;
        out[(size_t)r * 64 + o] = acc[rc] + ob;
    }
}

extern "C" void kernel_launch(void* const* d_in, const int* in_sizes, int n_in,
                              void* d_out, int out_size, void* d_ws, size_t ws_size,
                              hipStream_t stream) {
    const float* x      = (const float*)d_in[0];
    const float* f0     = (const float*)d_in[1];
    const float* w_ih_f = (const float*)d_in[2];
    const float* w_hh_f = (const float*)d_in[3];
    const float* b_f    = (const float*)d_in[4];
    const float* w_ih_b = (const float*)d_in[5];
    const float* w_hh_b = (const float*)d_in[6];
    const float* b_b    = (const float*)d_in[7];
    const float* ln_g   = (const float*)d_in[8];
    const float* ln_b   = (const float*)d_in[9];
    const float* out_w  = (const float*)d_in[10];
    const float* out_b  = (const float*)d_in[11];
    float* out = (float*)d_out;

    char* ws = (char*)d_ws;
    size_t off = 0;
    auto alloc = [&](size_t bytes) { size_t o = off; off = (off + bytes + 255) & ~(size_t)255; return o; };
    __bf16* A     = (__bf16*)(ws + alloc((size_t)16128 * 960 * 2));
    __bf16* BT    = (__bf16*)(ws + alloc((size_t)2176 * 960 * 2));
    __bf16* Cdft  = (__bf16*)(ws + alloc((size_t)16128 * 2176 * 2));
    __bf16* feat  = (__bf16*)(ws + alloc((size_t)16128 * 320 * 2));
    __bf16* WT    = (__bf16*)(ws + alloc((size_t)1024 * 320 * 2));
    // pre padded +-2 timesteps so the LSTM prefetch needs no bounds check
    float*  preA  = (float*)(ws + alloc((size_t)(1001 * 2 + 8) * 16 * 512 * 4));
    float*  pre   = preA + (size_t)4 * 16 * 512;
    float*  h_out = (float*)(ws + alloc((size_t)2 * 1001 * 16 * 128 * 4));
    (void)ws_size; (void)in_sizes; (void)n_in; (void)out_size;

    prep_kernel <<<39680, 256, 0, stream>>>(x, w_ih_f, w_ih_b, BT, A, WT);
    gemm_kernel <<<dim3(17, 126), 256, 0, stream>>>(A, BT, 960, 15, 0, Cdft, nullptr, nullptr, nullptr);
    build_feat  <<<16016, 320, 0, stream>>>(f0, Cdft, feat);
    gemm_kernel <<<dim3(8, 126), 256, 0, stream>>>(feat, WT, 320, 5, 1, nullptr, pre, b_f, b_b);
    lstm_kernel <<<32, 512, 0, stream>>>(w_hh_f, w_hh_b, pre, h_out);
    out_kernel  <<<1001, 256, 0, stream>>>(h_out, ln_g, ln_b, out_w, out_b, out);
}